// Round 1
// 3391.803 us; speedup vs baseline: 1.5127x; 1.5127x over previous
//
#include <hip/hip_runtime.h>

#define NEGV (-1e30f)
#define NM   ((size_t)513*65536)   // 33,619,968 logM elements
#define NF4  (NM/4)

typedef _Float16 h2 __attribute__((ext_vector_type(2)));

#if defined(__has_builtin)
#if __has_builtin(__builtin_amdgcn_fdot2)
#define HAS_FDOT2 1
#endif
#endif

__device__ __forceinline__ float dot2f(h2 a, h2 b, float c){
#ifdef HAS_FDOT2
  return __builtin_amdgcn_fdot2(a, b, c, false);
#else
  return c + (float)a.x*(float)b.x + (float)a.y*(float)b.y;
#endif
}

__device__ __forceinline__ h2 u2h2(unsigned u){ return __builtin_bit_cast(h2, u); }

// ---------------- workspace layout (all offsets in elements) ----------------
struct WS {
  float *fA, *fB, *fD, *fLZ;
  _Float16 *hA, *hB;
  unsigned char* idx8;
  unsigned long long *flagF8, *flagB8;   // hi32 = ready, lo32 = bits(row max)
  int *flagV, *ctr;
};
__device__ __forceinline__ WS get_ws(void* w){
  WS s;
  float* f = (float*)w;
  s.fA  = f;                 // log_alpha  [514][256] f32
  s.fB  = f + 131584;        // log_beta   [514][256] f32
  s.fD  = s.fB + 131584;     // vit delta  [512][256] f32
  s.fLZ = s.fD + 131072;     // logZ (+pad)
  s.hA  = (_Float16*)(s.fLZ + 64);   // exp(alpha-ma) mailbox [514][256] f16
  s.hB  = s.hA + 131584;             // exp(beta -mb) mailbox [514][256] f16
  s.idx8 = (unsigned char*)(s.hB + 131584);  // viterbi argmax [511][256] u8
  s.flagF8 = (unsigned long long*)(s.idx8 + 131072);
  s.flagB8 = s.flagF8 + 576;
  s.flagV  = (int*)(s.flagB8 + 576);
  s.ctr    = s.flagV + 576;
  return s;
}

__device__ __forceinline__ float block_max256(float v, float* sred){
  #pragma unroll
  for (int m2=32;m2>0;m2>>=1) v = fmaxf(v, __shfl_xor(v, m2, 64));
  if ((threadIdx.x & 63)==0) sred[threadIdx.x>>6] = v;
  __syncthreads();
  return fmaxf(fmaxf(sred[0],sred[1]), fmaxf(sred[2],sred[3]));
}
__device__ __forceinline__ float block_sum256(float v, float* sred){
  #pragma unroll
  for (int m2=32;m2>0;m2>>=1) v += __shfl_xor(v, m2, 64);
  if ((threadIdx.x & 63)==0) sred[4+(threadIdx.x>>6)] = v;
  __syncthreads();
  return sred[4]+sred[5]+sred[6]+sred[7];
}

// ---------------- K0: zero flags/counters, init boundary mailboxes ----------
__global__ __launch_bounds__(1024) void k0_init(void* wsv){
  WS s = get_ws(wsv);
  const int tid = threadIdx.x;
  for (int i=tid;i<576;i+=1024){ s.flagF8[i]=0ull; s.flagB8[i]=0ull; s.flagV[i]=0; }
  if (tid < 64) s.ctr[tid] = 0;
  __syncthreads();
  if (tid < 256){
    s.fA[tid] = (tid==0)?0.0f:NEGV;               // log_alpha[0] one-hot
    s.hA[tid] = (tid==0)?(_Float16)1.0f:(_Float16)0.0f;
    s.fB[(size_t)513*256+tid] = (tid==0)?0.0f:NEGV;   // log_beta[513] one-hot
    s.hB[(size_t)513*256+tid] = (tid==0)?(_Float16)1.0f:(_Float16)0.0f;
  }
  // packed flags: ready=1, row max = 0.0f (bits = 0)
  if (tid==0){ s.flagF8[0] = (1ull<<32); s.flagB8[513] = (1ull<<32); }
}

// ---------------- K1: logM = sum_k w_k f_k (+ boundary mask) into d_out -----
__global__ __launch_bounds__(1024) void k1_logM(const float* __restrict__ f,
                                                const float* __restrict__ w,
                                                float* __restrict__ lm, void* wsv){
  WS s = get_ws(wsv);
  const float w0=w[0], w1=w[1], w2=w[2], w3=w[3];
  const float4* f0=(const float4*)f;
  const float4* f1=f0+NF4; const float4* f2=f1+NF4; const float4* f3=f2+NF4;
  float4* o=(float4*)lm;
  for (size_t i=(size_t)blockIdx.x*1024+threadIdx.x; i<NF4; i+=(size_t)gridDim.x*1024){
    float4 a=f0[i], b=f1[i], c=f2[i], d=f3[i];
    float4 v;
    v.x = w0*a.x+w1*b.x+w2*c.x+w3*d.x;
    v.y = w0*a.y+w1*b.y+w2*c.y+w3*d.y;
    v.z = w0*a.z+w1*b.z+w2*c.z+w3*d.z;
    v.w = w0*a.w+w1*b.w+w2*c.w+w3*d.w;
    size_t e=i*4;
    int t=(int)(e>>16), r=(int)((e>>8)&255), cc=(int)(e&255);
    if (t==0 && r!=0){ v.x=NEGV; v.y=NEGV; v.z=NEGV; v.w=NEGV; }
    if (t==512){ if (cc!=0) v.x=NEGV; v.y=NEGV; v.z=NEGV; v.w=NEGV; }
    o[i]=v;
  }
  // seed viterbi chain: delta_0 = logM[0][0][:] (recomputed directly from f)
  if (blockIdx.x==0 && threadIdx.x<256){
    int j=threadIdx.x;
    float sv = w0*f[j] + w1*f[NM+j] + w2*f[2*NM+j] + w3*f[3*NM+j];
    s.fD[j]=sv;
    if (j==0) s.flagV[0]=1;   // visible to next kernel via dispatch boundary
  }
}

// ---------------- K2: three ticketed scan chains ----------------------------
// Handoff protocol: all cross-block data moves via RELAXED agent-scope atomics
// (sc1, bypass non-coherent L2) -> no buffer_inv / buffer_wbl2 anywhere.
// Producer: data stores (sc1) -> __syncthreads (drains vmcnt in every wave)
//           -> flag store (sc1). Consumer: relaxed poll -> compiler barrier
//           -> data loads (sc1).
__global__ __launch_bounds__(256,1) void chains_k(const float* __restrict__ lm, void* wsv){
  WS s = get_ws(wsv);
  __shared__ int s_t;
  __shared__ float s_bcast;
  __shared__ float sred[8];
  __shared__ __align__(16) unsigned aL32[128];
  __shared__ __align__(16) float dL[256];
  __shared__ __align__(16) float ldsM[32768];   // 128 KB viterbi row stage -> 1 blk/CU
  const int tid = threadIdx.x;
  const int role = blockIdx.x % 3;   // 0 fwd alpha, 1 bwd beta, 2 viterbi
  if (tid==0) s_t = atomicAdd(&s.ctr[role], 1);
  __syncthreads();
  const int tk = s_t;

  if (role==0){ // ---- forward log-alpha, step tk in [0,513) ----
    if (tk >= 513) return;
    const float* M = lm + (size_t)tk*65536;
    h2 P[128];                       // exp(logM[:,j]) for own column j=tid
    #pragma unroll
    for (int h=0;h<128;h++){
      float x0 = M[(size_t)(2*h  )*256 + tid];
      float x1 = M[(size_t)(2*h+1)*256 + tid];
      h2 v; v.x=(_Float16)fminf(__expf(x0),60000.0f);
            v.y=(_Float16)fminf(__expf(x1),60000.0f);
      P[h]=v;
    }
    asm volatile("s_waitcnt vmcnt(0)" ::: "memory");   // pin preload before spin
    unsigned* hA32 = (unsigned*)s.hA;
    if (tid<128){
      unsigned long long v;
      while ((unsigned)((v=__hip_atomic_load(&s.flagF8[tk],__ATOMIC_RELAXED,__HIP_MEMORY_SCOPE_AGENT))>>32)==0u)
        __builtin_amdgcn_s_sleep(1);
      asm volatile("" ::: "memory");                   // no reorder of mailbox load above poll
      if (tid==0) s_bcast = __uint_as_float((unsigned)v);
      aL32[tid] = __hip_atomic_load(hA32 + (size_t)tk*128 + tid,
                                    __ATOMIC_RELAXED, __HIP_MEMORY_SCOPE_AGENT);
    }
    __syncthreads();
    const float ma = s_bcast;
    float ac0=0.0f, ac1=0.0f, ac2=0.0f, ac3=0.0f;     // 4 chains: 32-deep each
    const uint4* a4 = (const uint4*)aL32;
    #pragma unroll
    for (int q=0;q<32;q++){
      uint4 av = a4[q];
      ac0 = dot2f(P[4*q+0], u2h2(av.x), ac0);
      ac1 = dot2f(P[4*q+1], u2h2(av.y), ac1);
      ac2 = dot2f(P[4*q+2], u2h2(av.z), ac2);
      ac3 = dot2f(P[4*q+3], u2h2(av.w), ac3);
    }
    float alpha = ma + __logf((ac0+ac1)+(ac2+ac3));
    s.fA[(size_t)(tk+1)*256 + tid] = alpha;           // K3-only: plain store
    float m = block_max256(alpha, sred);
    float e = __expf(alpha - m);
    unsigned short hu = __builtin_bit_cast(unsigned short, (_Float16)e);
    unsigned po = (unsigned)__shfl_xor((int)hu, 1, 64);
    if ((tid&1)==0)
      __hip_atomic_store(hA32 + (size_t)(tk+1)*128 + (tid>>1),
                         (unsigned)hu | (po<<16),
                         __ATOMIC_RELAXED, __HIP_MEMORY_SCOPE_AGENT);
    if (tk==512){
      float sm = block_sum256(e, sred);
      if (tid==0) s.fLZ[0] = m + __logf(sm);
    }
    __syncthreads();   // drains vmcnt in every wave -> mailbox stores acked
    if (tid==0)
      __hip_atomic_store(&s.flagF8[tk+1],
                         ((unsigned long long)1<<32) | (unsigned long long)__float_as_uint(m),
                         __ATOMIC_RELAXED, __HIP_MEMORY_SCOPE_AGENT);

  } else if (role==1){ // ---- backward log-beta, ticket tk -> t=512-tk ----
    if (tk >= 513) return;
    const int tt = 512 - tk;
    const float* M = lm + (size_t)tt*65536;
    const float2* r2 = (const float2*)(M + (size_t)tid*256);  // own row i=tid
    h2 P[128];
    #pragma unroll
    for (int h=0;h<128;h++){
      float2 x = r2[h];
      h2 v; v.x=(_Float16)fminf(__expf(x.x),60000.0f);
            v.y=(_Float16)fminf(__expf(x.y),60000.0f);
      P[h]=v;
    }
    asm volatile("s_waitcnt vmcnt(0)" ::: "memory");
    unsigned* hB32 = (unsigned*)s.hB;
    if (tid<128){
      unsigned long long v;
      while ((unsigned)((v=__hip_atomic_load(&s.flagB8[tt+1],__ATOMIC_RELAXED,__HIP_MEMORY_SCOPE_AGENT))>>32)==0u)
        __builtin_amdgcn_s_sleep(1);
      asm volatile("" ::: "memory");
      if (tid==0) s_bcast = __uint_as_float((unsigned)v);
      aL32[tid] = __hip_atomic_load(hB32 + (size_t)(tt+1)*128 + tid,
                                    __ATOMIC_RELAXED, __HIP_MEMORY_SCOPE_AGENT);
    }
    __syncthreads();
    const float mb = s_bcast;
    float ac0=0.0f, ac1=0.0f, ac2=0.0f, ac3=0.0f;
    const uint4* a4 = (const uint4*)aL32;
    #pragma unroll
    for (int q=0;q<32;q++){
      uint4 av = a4[q];
      ac0 = dot2f(P[4*q+0], u2h2(av.x), ac0);
      ac1 = dot2f(P[4*q+1], u2h2(av.y), ac1);
      ac2 = dot2f(P[4*q+2], u2h2(av.z), ac2);
      ac3 = dot2f(P[4*q+3], u2h2(av.w), ac3);
    }
    float lbv = mb + __logf((ac0+ac1)+(ac2+ac3));
    s.fB[(size_t)tt*256 + tid] = lbv;                 // K3-only: plain store
    float m = block_max256(lbv, sred);
    float e = __expf(lbv - m);
    unsigned short hu = __builtin_bit_cast(unsigned short, (_Float16)e);
    unsigned po = (unsigned)__shfl_xor((int)hu, 1, 64);
    if ((tid&1)==0)
      __hip_atomic_store(hB32 + (size_t)tt*128 + (tid>>1),
                         (unsigned)hu | (po<<16),
                         __ATOMIC_RELAXED, __HIP_MEMORY_SCOPE_AGENT);
    __syncthreads();
    if (tid==0)
      __hip_atomic_store(&s.flagB8[tt],
                         ((unsigned long long)1<<32) | (unsigned long long)__float_as_uint(m),
                         __ATOMIC_RELAXED, __HIP_MEMORY_SCOPE_AGENT);

  } else { // ---- viterbi max-plus, ticket tk in [0,511), matrix logM[tk+1] ----
    if (tk >= 511) return;
    const float* M = lm + (size_t)(tk+1)*65536;
    // rows 0..127 of own column in registers (fits: 128 VGPR); rows 128..255 in LDS
    float Pa[128];
    #pragma unroll
    for (int i=0;i<128;i++) Pa[i] = M[(size_t)i*256 + tid];
    {
      const float4* g4 = (const float4*)(M + 32768);
      float4* l4 = (float4*)ldsM;
      #pragma unroll
      for (int q=0;q<32;q++) l4[q*256 + tid] = g4[q*256 + tid];
    }
    asm volatile("s_waitcnt vmcnt(0)" ::: "memory");   // pin ALL preloads before spin
    while (__hip_atomic_load(&s.flagV[tk],__ATOMIC_RELAXED,__HIP_MEMORY_SCOPE_AGENT)==0)
      __builtin_amdgcn_s_sleep(1);
    asm volatile("" ::: "memory");
    dL[tid] = __hip_atomic_load(s.fD + (size_t)tk*256 + tid,
                                __ATOMIC_RELAXED, __HIP_MEMORY_SCOPE_AGENT);
    __syncthreads();   // dL visible + LDS stage (lgkmcnt) drained
    const float4* d4 = (const float4*)dL;
    float b0=-3.0e38f, b1=-3.0e38f, b2=-3.0e38f, b3=-3.0e38f;
    #pragma unroll
    for (int q=0;q<32;q++){
      float4 dv = d4[q];
      b0 = fmaxf(b0, dv.x + Pa[4*q+0]);
      b1 = fmaxf(b1, dv.y + Pa[4*q+1]);
      b2 = fmaxf(b2, dv.z + Pa[4*q+2]);
      b3 = fmaxf(b3, dv.w + Pa[4*q+3]);
    }
    #pragma unroll
    for (int q=0;q<32;q++){
      float4 dv = d4[32+q];
      b0 = fmaxf(b0, dv.x + ldsM[(4*q+0)*256 + tid]);
      b1 = fmaxf(b1, dv.y + ldsM[(4*q+1)*256 + tid]);
      b2 = fmaxf(b2, dv.z + ldsM[(4*q+2)*256 + tid]);
      b3 = fmaxf(b3, dv.w + ldsM[(4*q+3)*256 + tid]);
    }
    float best = fmaxf(fmaxf(b0,b1),fmaxf(b2,b3));
    __hip_atomic_store(s.fD + (size_t)(tk+1)*256 + tid, best,
                       __ATOMIC_RELAXED, __HIP_MEMORY_SCOPE_AGENT);
    __syncthreads();   // drain delta stores in every wave
    if (tid==0)
      __hip_atomic_store(&s.flagV[tk+1], 1, __ATOMIC_RELAXED, __HIP_MEMORY_SCOPE_AGENT);
    // argmax extraction off the chain critical path (first max index, like np)
    int bi = 0;
    #pragma unroll
    for (int r=127;r>=0;r--){ float v = dL[128+r] + ldsM[r*256 + tid]; bi = (v==best)? 128+r : bi; }
    #pragma unroll
    for (int i=127;i>=0;i--){ float v = dL[i] + Pa[i]; bi = (v==best)? i : bi; }
    s.idx8[(size_t)tk*256 + tid] = (unsigned char)bi;
  }
}

// ---------------- K3: p12 in place + viterbi backtrack ----------------------
__global__ __launch_bounds__(1024) void k3_epilogue(float* __restrict__ pm, void* wsv,
                                                    float* __restrict__ pathOut){
  WS s = get_ws(wsv);
  __shared__ unsigned char sidx[65280];
  __shared__ int s_y;
  if (blockIdx.x == 0){
    const int tid = threadIdx.x;
    // phase 1: idx rows 256..510 staged in LDS
    for (int i=tid;i<255*256;i+=1024) sidx[i] = s.idx8[(size_t)256*256 + i];
    __syncthreads();
    if (tid==0){
      const float* dT = s.fD + (size_t)511*256;
      float best = dT[0]; int last = 0;
      for (int j=1;j<256;j++){ float v=dT[j]; if (v>best){best=v;last=j;} }
      pathOut[511] = (float)last;
      int y = last;
      for (int rr=510;rr>=256;rr--){ y = sidx[(rr-256)*256 + y]; pathOut[rr]=(float)y; }
      s_y = y;
    }
    __syncthreads();
    // phase 2: idx rows 1..255
    for (int i=tid;i<255*256;i+=1024) sidx[i] = s.idx8[256 + i];
    __syncthreads();
    if (tid==0){
      int y = s_y;
      for (int rr=255;rr>=1;rr--){ y = sidx[(rr-1)*256 + y]; pathOut[rr]=(float)y; }
      y = s.idx8[y];            // row 0 direct from global
      pathOut[0] = (float)y;
    }
    return;
  }
  const float lz = s.fLZ[0];
  for (size_t i=(size_t)(blockIdx.x-1)*1024+threadIdx.x; i<NF4; i+=(size_t)(gridDim.x-1)*1024){
    size_t e = i*4;
    int t=(int)(e>>16), r=(int)((e>>8)&255), cc=(int)(e&255);
    float la = s.fA[(size_t)t*256 + r];
    float4 lb4 = *(const float4*)(s.fB + (size_t)(t+1)*256 + cc);
    float4 m4 = ((const float4*)pm)[i];
    float base = la - lz;
    float4 o;
    o.x = __expf(base + m4.x + lb4.x);
    o.y = __expf(base + m4.y + lb4.y);
    o.z = __expf(base + m4.z + lb4.z);
    o.w = __expf(base + m4.w + lb4.w);
    ((float4*)pm)[i] = o;
  }
}

extern "C" void kernel_launch(void* const* d_in, const int* in_sizes, int n_in,
                              void* d_out, int out_size, void* d_ws, size_t ws_size,
                              hipStream_t stream){
  const float* f = (const float*)d_in[0];
  const float* w = (const float*)d_in[1];
  float* out  = (float*)d_out;
  float* lm   = out;                        // logM lives in the p12 region, overwritten in place
  float* path = out + (out_size - 512);
  hipLaunchKernelGGL(k0_init,   dim3(1),    dim3(1024), 0, stream, d_ws);
  hipLaunchKernelGGL(k1_logM,   dim3(8208), dim3(1024), 0, stream, f, w, lm, d_ws);
  hipLaunchKernelGGL(chains_k,  dim3(1539), dim3(256),  0, stream, lm, d_ws);
  hipLaunchKernelGGL(k3_epilogue, dim3(8209), dim3(1024), 0, stream, lm, d_ws, path);
}

// Round 2
// 3104.666 us; speedup vs baseline: 1.6526x; 1.0925x over previous
//
#include <hip/hip_runtime.h>

#define NEGV (-1e30f)
#define NM   ((size_t)513*65536)   // 33,619,968 logM elements
#define NF4  (NM/4)
#define SENT 0xFFFFFFFFu           // poll sentinel: NaN pattern, unreachable by real data

typedef _Float16 h2 __attribute__((ext_vector_type(2)));

#if defined(__has_builtin)
#if __has_builtin(__builtin_amdgcn_fdot2)
#define HAS_FDOT2 1
#endif
#endif

__device__ __forceinline__ float dot2f(h2 a, h2 b, float c){
#ifdef HAS_FDOT2
  return __builtin_amdgcn_fdot2(a, b, c, false);
#else
  return c + (float)a.x*(float)b.x + (float)a.y*(float)b.y;
#endif
}

__device__ __forceinline__ h2 u2h2(unsigned u){ return __builtin_bit_cast(h2, u); }

// ---------------- workspace layout (all offsets in elements) ----------------
struct WS {
  float *fA, *fB, *fD, *fLZ;
  _Float16 *hA, *hB;
  unsigned char* idx8;
  unsigned long long *flagF8, *flagB8;   // hi32 = ready, lo32 = bits(row max)
  int *flagV, *ctr;                      // flagV unused (kept for layout stability)
};
__device__ __forceinline__ WS get_ws(void* w){
  WS s;
  float* f = (float*)w;
  s.fA  = f;                 // log_alpha  [514][256] f32
  s.fB  = f + 131584;        // log_beta   [514][256] f32
  s.fD  = s.fB + 131584;     // vit delta  [512][256] f32 (poll-on-data, sentinel-armed)
  s.fLZ = s.fD + 131072;     // logZ (+pad)
  s.hA  = (_Float16*)(s.fLZ + 64);   // exp(alpha-ma) mailbox [514][256] f16 (sentinel-armed)
  s.hB  = s.hA + 131584;             // exp(beta -mb) mailbox [514][256] f16 (sentinel-armed)
  s.idx8 = (unsigned char*)(s.hB + 131584);  // viterbi argmax [511][256] u8
  s.flagF8 = (unsigned long long*)(s.idx8 + 131072);
  s.flagB8 = s.flagF8 + 576;
  s.flagV  = (int*)(s.flagB8 + 576);
  s.ctr    = s.flagV + 576;
  return s;
}

__device__ __forceinline__ float block_max256(float v, float* sred){
  #pragma unroll
  for (int m2=32;m2>0;m2>>=1) v = fmaxf(v, __shfl_xor(v, m2, 64));
  if ((threadIdx.x & 63)==0) sred[threadIdx.x>>6] = v;
  __syncthreads();
  return fmaxf(fmaxf(sred[0],sred[1]), fmaxf(sred[2],sred[3]));
}
__device__ __forceinline__ float block_sum256(float v, float* sred){
  #pragma unroll
  for (int m2=32;m2>0;m2>>=1) v += __shfl_xor(v, m2, 64);
  if ((threadIdx.x & 63)==0) sred[4+(threadIdx.x>>6)] = v;
  __syncthreads();
  return sred[4]+sred[5]+sred[6]+sred[7];
}

// ---------------- K0: arm sentinels, zero flags, init boundary rows ---------
// Sentinel regions and boundary regions are DISJOINT -> no cross-block ordering needed.
__global__ __launch_bounds__(1024) void k0_init(void* wsv){
  WS s = get_ws(wsv);
  unsigned* hA32 = (unsigned*)s.hA;          // 514*128 dwords
  unsigned* hB32 = (unsigned*)s.hB;
  unsigned* fD32 = (unsigned*)s.fD;          // 512*256 dwords
  const size_t g = (size_t)blockIdx.x*1024 + threadIdx.x;
  const size_t stride = (size_t)gridDim.x*1024;
  for (size_t i=g; i<65664;  i+=stride) hA32[128+i] = SENT;   // rows 1..513
  for (size_t i=g; i<65664;  i+=stride) hB32[i]     = SENT;   // rows 0..512
  for (size_t i=g; i<130816; i+=stride) fD32[256+i] = SENT;   // rows 1..511
  if (blockIdx.x==0){
    const int tid = threadIdx.x;
    for (int i=tid;i<576;i+=1024){ s.flagF8[i]=0ull; s.flagB8[i]=0ull; }
    if (tid < 64) s.ctr[tid] = 0;
    if (tid < 256){
      s.fA[tid] = (tid==0)?0.0f:NEGV;               // log_alpha[0] one-hot
      s.hA[tid] = (tid==0)?(_Float16)1.0f:(_Float16)0.0f;
      s.fB[(size_t)513*256+tid] = (tid==0)?0.0f:NEGV;   // log_beta[513] one-hot
      s.hB[(size_t)513*256+tid] = (tid==0)?(_Float16)1.0f:(_Float16)0.0f;
    }
    if (tid==0){ s.flagF8[0] = (1ull<<32); s.flagB8[513] = (1ull<<32); }
  }
}

// ---------------- K1: logM = sum_k w_k f_k (+ boundary mask) into d_out -----
__global__ __launch_bounds__(1024) void k1_logM(const float* __restrict__ f,
                                                const float* __restrict__ w,
                                                float* __restrict__ lm, void* wsv){
  WS s = get_ws(wsv);
  const float w0=w[0], w1=w[1], w2=w[2], w3=w[3];
  const float4* f0=(const float4*)f;
  const float4* f1=f0+NF4; const float4* f2=f1+NF4; const float4* f3=f2+NF4;
  float4* o=(float4*)lm;
  for (size_t i=(size_t)blockIdx.x*1024+threadIdx.x; i<NF4; i+=(size_t)gridDim.x*1024){
    float4 a=f0[i], b=f1[i], c=f2[i], d=f3[i];
    float4 v;
    v.x = w0*a.x+w1*b.x+w2*c.x+w3*d.x;
    v.y = w0*a.y+w1*b.y+w2*c.y+w3*d.y;
    v.z = w0*a.z+w1*b.z+w2*c.z+w3*d.z;
    v.w = w0*a.w+w1*b.w+w2*c.w+w3*d.w;
    size_t e=i*4;
    int t=(int)(e>>16), r=(int)((e>>8)&255), cc=(int)(e&255);
    if (t==0 && r!=0){ v.x=NEGV; v.y=NEGV; v.z=NEGV; v.w=NEGV; }
    if (t==512){ if (cc!=0) v.x=NEGV; v.y=NEGV; v.z=NEGV; v.w=NEGV; }
    o[i]=v;
  }
  // seed viterbi chain: delta_0 = logM[0][0][:] (recomputed directly from f)
  // plain stores; visible to chains_k at the dispatch boundary (L2 flush)
  if (blockIdx.x==0 && threadIdx.x<256){
    int j=threadIdx.x;
    float sv = w0*f[j] + w1*f[NM+j] + w2*f[2*NM+j] + w3*f[3*NM+j];
    s.fD[j]=sv;
  }
}

// ---------------- K2: three ticketed scan chains ----------------------------
// Handoff protocol: POLL-ON-DATA. Mailboxes/deltas are sentinel-armed by K0;
// each consumer lane spins on ITS OWN dword (sc1, relaxed agent scope). The
// successful poll IS the data read -> one L3 round trip per step. Producers
// fire-and-forget (no vmcnt drain, no ordering): every dword is independently
// validated. Row max rides in flagF8/flagB8, polled by a separate wave in
// parallel with the data poll.
__global__ __launch_bounds__(256,1) void chains_k(const float* __restrict__ lm, void* wsv){
  WS s = get_ws(wsv);
  __shared__ int s_t;
  __shared__ float s_bcast;
  __shared__ float sred[8];
  __shared__ __align__(16) unsigned aL32[128];
  __shared__ __align__(16) float dL[256];
  __shared__ __align__(16) float ldsM[32768];   // 128 KB viterbi row stage -> 1 blk/CU
  const int tid = threadIdx.x;
  const int role = blockIdx.x % 3;   // 0 fwd alpha, 1 bwd beta, 2 viterbi
  if (tid==0) s_t = atomicAdd(&s.ctr[role], 1);
  __syncthreads();
  const int tk = s_t;

  if (role==0){ // ---- forward log-alpha, step tk in [0,513) ----
    if (tk >= 513) return;
    const float* M = lm + (size_t)tk*65536;
    h2 P[128];                       // exp(logM[:,j]) for own column j=tid
    #pragma unroll
    for (int h=0;h<128;h++){
      float x0 = M[(size_t)(2*h  )*256 + tid];
      float x1 = M[(size_t)(2*h+1)*256 + tid];
      h2 v; v.x=(_Float16)fminf(__expf(x0),60000.0f);
            v.y=(_Float16)fminf(__expf(x1),60000.0f);
      P[h]=v;
    }
    asm volatile("s_waitcnt vmcnt(0)" ::: "memory");   // pin preload before spin
    unsigned* hA32 = (unsigned*)s.hA;
    if (tid<128){                                      // waves 0,1: poll own mailbox dword
      const unsigned* mp = hA32 + (size_t)tk*128 + tid;
      unsigned mv = __hip_atomic_load(mp,__ATOMIC_RELAXED,__HIP_MEMORY_SCOPE_AGENT);
      while (mv==SENT){
        __builtin_amdgcn_s_sleep(1);
        mv = __hip_atomic_load(mp,__ATOMIC_RELAXED,__HIP_MEMORY_SCOPE_AGENT);
      }
      aL32[tid] = mv;
    } else if (tid==128){                              // wave 2: poll row-max flag
      unsigned long long v = __hip_atomic_load(&s.flagF8[tk],__ATOMIC_RELAXED,__HIP_MEMORY_SCOPE_AGENT);
      while ((unsigned)(v>>32)==0u){
        __builtin_amdgcn_s_sleep(1);
        v = __hip_atomic_load(&s.flagF8[tk],__ATOMIC_RELAXED,__HIP_MEMORY_SCOPE_AGENT);
      }
      s_bcast = __uint_as_float((unsigned)v);
    }
    __syncthreads();
    const float ma = s_bcast;
    float ac0=0.0f, ac1=0.0f, ac2=0.0f, ac3=0.0f;     // 4 chains: 32-deep each
    const uint4* a4 = (const uint4*)aL32;
    #pragma unroll
    for (int q=0;q<32;q++){
      uint4 av = a4[q];
      ac0 = dot2f(P[4*q+0], u2h2(av.x), ac0);
      ac1 = dot2f(P[4*q+1], u2h2(av.y), ac1);
      ac2 = dot2f(P[4*q+2], u2h2(av.z), ac2);
      ac3 = dot2f(P[4*q+3], u2h2(av.w), ac3);
    }
    float alpha = ma + __logf((ac0+ac1)+(ac2+ac3));
    s.fA[(size_t)(tk+1)*256 + tid] = alpha;           // K3-only: plain store, fire
    float m = block_max256(alpha, sred);
    if (tid==0)                                        // flag fires early (independent of mailbox)
      __hip_atomic_store(&s.flagF8[tk+1],
                         ((unsigned long long)1<<32) | (unsigned long long)__float_as_uint(m),
                         __ATOMIC_RELAXED, __HIP_MEMORY_SCOPE_AGENT);
    float e = __expf(alpha - m);
    unsigned short hu = __builtin_bit_cast(unsigned short, (_Float16)e);
    unsigned po = (unsigned)__shfl_xor((int)hu, 1, 64);
    if ((tid&1)==0)                                    // mailbox: fire-and-forget
      __hip_atomic_store(hA32 + (size_t)(tk+1)*128 + (tid>>1),
                         (unsigned)hu | (po<<16),
                         __ATOMIC_RELAXED, __HIP_MEMORY_SCOPE_AGENT);
    if (tk==512){
      float sm = block_sum256(e, sred);
      if (tid==0) s.fLZ[0] = m + __logf(sm);
    }

  } else if (role==1){ // ---- backward log-beta, ticket tk -> t=512-tk ----
    if (tk >= 513) return;
    const int tt = 512 - tk;
    const float* M = lm + (size_t)tt*65536;
    const float2* r2 = (const float2*)(M + (size_t)tid*256);  // own row i=tid
    h2 P[128];
    #pragma unroll
    for (int h=0;h<128;h++){
      float2 x = r2[h];
      h2 v; v.x=(_Float16)fminf(__expf(x.x),60000.0f);
            v.y=(_Float16)fminf(__expf(x.y),60000.0f);
      P[h]=v;
    }
    asm volatile("s_waitcnt vmcnt(0)" ::: "memory");
    unsigned* hB32 = (unsigned*)s.hB;
    if (tid<128){
      const unsigned* mp = hB32 + (size_t)(tt+1)*128 + tid;
      unsigned mv = __hip_atomic_load(mp,__ATOMIC_RELAXED,__HIP_MEMORY_SCOPE_AGENT);
      while (mv==SENT){
        __builtin_amdgcn_s_sleep(1);
        mv = __hip_atomic_load(mp,__ATOMIC_RELAXED,__HIP_MEMORY_SCOPE_AGENT);
      }
      aL32[tid] = mv;
    } else if (tid==128){
      unsigned long long v = __hip_atomic_load(&s.flagB8[tt+1],__ATOMIC_RELAXED,__HIP_MEMORY_SCOPE_AGENT);
      while ((unsigned)(v>>32)==0u){
        __builtin_amdgcn_s_sleep(1);
        v = __hip_atomic_load(&s.flagB8[tt+1],__ATOMIC_RELAXED,__HIP_MEMORY_SCOPE_AGENT);
      }
      s_bcast = __uint_as_float((unsigned)v);
    }
    __syncthreads();
    const float mb = s_bcast;
    float ac0=0.0f, ac1=0.0f, ac2=0.0f, ac3=0.0f;
    const uint4* a4 = (const uint4*)aL32;
    #pragma unroll
    for (int q=0;q<32;q++){
      uint4 av = a4[q];
      ac0 = dot2f(P[4*q+0], u2h2(av.x), ac0);
      ac1 = dot2f(P[4*q+1], u2h2(av.y), ac1);
      ac2 = dot2f(P[4*q+2], u2h2(av.z), ac2);
      ac3 = dot2f(P[4*q+3], u2h2(av.w), ac3);
    }
    float lbv = mb + __logf((ac0+ac1)+(ac2+ac3));
    s.fB[(size_t)tt*256 + tid] = lbv;                 // K3-only: plain store, fire
    float m = block_max256(lbv, sred);
    if (tid==0)
      __hip_atomic_store(&s.flagB8[tt],
                         ((unsigned long long)1<<32) | (unsigned long long)__float_as_uint(m),
                         __ATOMIC_RELAXED, __HIP_MEMORY_SCOPE_AGENT);
    float e = __expf(lbv - m);
    unsigned short hu = __builtin_bit_cast(unsigned short, (_Float16)e);
    unsigned po = (unsigned)__shfl_xor((int)hu, 1, 64);
    if ((tid&1)==0)
      __hip_atomic_store(hB32 + (size_t)tt*128 + (tid>>1),
                         (unsigned)hu | (po<<16),
                         __ATOMIC_RELAXED, __HIP_MEMORY_SCOPE_AGENT);

  } else { // ---- viterbi max-plus, ticket tk in [0,511), matrix logM[tk+1] ----
    if (tk >= 511) return;
    const float* M = lm + (size_t)(tk+1)*65536;
    // rows 0..127 of own column in registers; rows 128..255 staged in LDS
    float Pa[128];
    #pragma unroll
    for (int i=0;i<128;i++) Pa[i] = M[(size_t)i*256 + tid];
    {
      const float4* g4 = (const float4*)(M + 32768);
      float4* l4 = (float4*)ldsM;
      #pragma unroll
      for (int q=0;q<32;q++) l4[q*256 + tid] = g4[q*256 + tid];
    }
    asm volatile("s_waitcnt vmcnt(0)" ::: "memory");   // pin ALL preloads before spin
    {
      const unsigned* dp = (const unsigned*)s.fD + (size_t)tk*256 + tid;  // poll own delta dword
      unsigned dv = __hip_atomic_load(dp,__ATOMIC_RELAXED,__HIP_MEMORY_SCOPE_AGENT);
      while (dv==SENT){
        __builtin_amdgcn_s_sleep(1);
        dv = __hip_atomic_load(dp,__ATOMIC_RELAXED,__HIP_MEMORY_SCOPE_AGENT);
      }
      dL[tid] = __uint_as_float(dv);
    }
    __syncthreads();   // dL visible + LDS stage (lgkmcnt) drained
    const float4* d4 = (const float4*)dL;
    float b0=-3.0e38f, b1=-3.0e38f, b2=-3.0e38f, b3=-3.0e38f;
    #pragma unroll
    for (int q=0;q<32;q++){
      float4 dv = d4[q];
      b0 = fmaxf(b0, dv.x + Pa[4*q+0]);
      b1 = fmaxf(b1, dv.y + Pa[4*q+1]);
      b2 = fmaxf(b2, dv.z + Pa[4*q+2]);
      b3 = fmaxf(b3, dv.w + Pa[4*q+3]);
    }
    #pragma unroll
    for (int q=0;q<32;q++){
      float4 dv = d4[32+q];
      b0 = fmaxf(b0, dv.x + ldsM[(4*q+0)*256 + tid]);
      b1 = fmaxf(b1, dv.y + ldsM[(4*q+1)*256 + tid]);
      b2 = fmaxf(b2, dv.z + ldsM[(4*q+2)*256 + tid]);
      b3 = fmaxf(b3, dv.w + ldsM[(4*q+3)*256 + tid]);
    }
    float best = fmaxf(fmaxf(b0,b1),fmaxf(b2,b3));
    __hip_atomic_store((unsigned*)s.fD + (size_t)(tk+1)*256 + tid,
                       __float_as_uint(best),
                       __ATOMIC_RELAXED, __HIP_MEMORY_SCOPE_AGENT);   // fire: this IS the handoff
    // argmax extraction off the chain critical path (first max index, like np)
    int bi = 0;
    #pragma unroll
    for (int r=127;r>=0;r--){ float v = dL[128+r] + ldsM[r*256 + tid]; bi = (v==best)? 128+r : bi; }
    #pragma unroll
    for (int i=127;i>=0;i--){ float v = dL[i] + Pa[i]; bi = (v==best)? i : bi; }
    s.idx8[(size_t)tk*256 + tid] = (unsigned char)bi;
  }
}

// ---------------- K3: p12 in place + viterbi backtrack ----------------------
__global__ __launch_bounds__(1024) void k3_epilogue(float* __restrict__ pm, void* wsv,
                                                    float* __restrict__ pathOut){
  WS s = get_ws(wsv);
  __shared__ unsigned char sidx[65280];
  __shared__ int s_y;
  if (blockIdx.x == 0){
    const int tid = threadIdx.x;
    // phase 1: idx rows 256..510 staged in LDS
    for (int i=tid;i<255*256;i+=1024) sidx[i] = s.idx8[(size_t)256*256 + i];
    __syncthreads();
    if (tid==0){
      const float* dT = s.fD + (size_t)511*256;
      float best = dT[0]; int last = 0;
      for (int j=1;j<256;j++){ float v=dT[j]; if (v>best){best=v;last=j;} }
      pathOut[511] = (float)last;
      int y = last;
      for (int rr=510;rr>=256;rr--){ y = sidx[(rr-256)*256 + y]; pathOut[rr]=(float)y; }
      s_y = y;
    }
    __syncthreads();
    // phase 2: idx rows 1..255
    for (int i=tid;i<255*256;i+=1024) sidx[i] = s.idx8[256 + i];
    __syncthreads();
    if (tid==0){
      int y = s_y;
      for (int rr=255;rr>=1;rr--){ y = sidx[(rr-1)*256 + y]; pathOut[rr]=(float)y; }
      y = s.idx8[y];            // row 0 direct from global
      pathOut[0] = (float)y;
    }
    return;
  }
  const float lz = s.fLZ[0];
  for (size_t i=(size_t)(blockIdx.x-1)*1024+threadIdx.x; i<NF4; i+=(size_t)(gridDim.x-1)*1024){
    size_t e = i*4;
    int t=(int)(e>>16), r=(int)((e>>8)&255), cc=(int)(e&255);
    float la = s.fA[(size_t)t*256 + r];
    float4 lb4 = *(const float4*)(s.fB + (size_t)(t+1)*256 + cc);
    float4 m4 = ((const float4*)pm)[i];
    float base = la - lz;
    float4 o;
    o.x = __expf(base + m4.x + lb4.x);
    o.y = __expf(base + m4.y + lb4.y);
    o.z = __expf(base + m4.z + lb4.z);
    o.w = __expf(base + m4.w + lb4.w);
    ((float4*)pm)[i] = o;
  }
}

extern "C" void kernel_launch(void* const* d_in, const int* in_sizes, int n_in,
                              void* d_out, int out_size, void* d_ws, size_t ws_size,
                              hipStream_t stream){
  const float* f = (const float*)d_in[0];
  const float* w = (const float*)d_in[1];
  float* out  = (float*)d_out;
  float* lm   = out;                        // logM lives in the p12 region, overwritten in place
  float* path = out + (out_size - 512);
  hipLaunchKernelGGL(k0_init,   dim3(128),  dim3(1024), 0, stream, d_ws);
  hipLaunchKernelGGL(k1_logM,   dim3(8208), dim3(1024), 0, stream, f, w, lm, d_ws);
  hipLaunchKernelGGL(chains_k,  dim3(1539), dim3(256),  0, stream, lm, d_ws);
  hipLaunchKernelGGL(k3_epilogue, dim3(8209), dim3(1024), 0, stream, lm, d_ws, path);
}